// Round 6
// baseline (782.619 us; speedup 1.0000x reference)
//
#include <hip/hip_runtime.h>
#include <hip/hip_bf16.h>

typedef __attribute__((ext_vector_type(8))) _Float16 f16x8;
typedef __attribute__((ext_vector_type(4))) float f32x4;
typedef __attribute__((ext_vector_type(4))) unsigned short us4;
typedef __attribute__((ext_vector_type(8))) unsigned short us8;

#define B_   32
#define C_   1536
#define CI_  768
#define N_   784
#define S_   196
#define MP_  224
#define MK_  196

__device__ __forceinline__ unsigned short f2h(float f) {
    _Float16 h = (_Float16)f;      // v_cvt_f16_f32, RTNE
    return __builtin_bit_cast(unsigned short, h);
}
__device__ __forceinline__ f32x4 mfma_f16(f16x8 a, f16x8 b, f32x4 c) {
    return __builtin_amdgcn_mfma_f32_16x16x32_f16(a, b, c, 0, 0, 0);
}
// async 16B global->LDS: per-lane global addr, wave-uniform LDS base;
// HW writes lane l's 16B to base + l*16 (layouts below are lane-ordered).
__device__ __forceinline__ void gl_lds16(const unsigned short* g, unsigned short* l) {
    __builtin_amdgcn_global_load_lds(
        (const __attribute__((address_space(1))) unsigned int*)g,
        (__attribute__((address_space(3))) unsigned int*)l, 16, 0, 0);
}

// Stage B only (112 rows x 32 K): 7 chunks of 1KB (16 rows x 4 x 16B).
// T2 swizzle: source 16B-column is l4c ^ ((l4r>>1)&3); LDS linear; reader
// XORs back via rcol.
__device__ __forceinline__ void stageB7(const unsigned short* Brow,
                                        unsigned short* B_s, int k0,
                                        int wv, int l4r, int l4c_sw) {
    for (int c = wv; c < 7; c += 4) {
        gl_lds16(Brow + (size_t)(c * 16 + l4r) * C_ + k0 + l4c_sw * 8,
                 B_s + c * 512);
    }
}

// 24-chunk A+B variant for k_final (B padded to 128 rows) -> 6 chunks/wave,
// wave-uniform vmcnt.
__device__ __forceinline__ void stage24(const unsigned short* Arow,
                                        const unsigned short* Brow,
                                        unsigned short* A_s, unsigned short* B_s,
                                        int k0, int stride,
                                        int wv, int l4r, int l4c_sw) {
    for (int c = wv; c < 24; c += 4) {
        if (c < 16) {
            gl_lds16(Arow + (size_t)(c * 16 + l4r) * stride + k0 + l4c_sw * 8,
                     A_s + c * 512);
        } else {
            int cb = c - 16;
            gl_lds16(Brow + (size_t)(cb * 16 + l4r) * stride + k0 + l4c_sw * 8,
                     B_s + cb * 512);
        }
    }
}

// Counted-wait + raw barrier (T3/T4) for the 3-buffer k_final pipeline.
#define PIPE_WAIT_BARRIER()                                   \
    do {                                                      \
        asm volatile("s_waitcnt vmcnt(6)" ::: "memory");      \
        __builtin_amdgcn_s_barrier();                         \
        __builtin_amdgcn_sched_barrier(0);                    \
    } while (0)

// ---------------------------------------------------------------------------
// fp32 -> fp16 weight pre-convert (count4 = #float4 units)
// ---------------------------------------------------------------------------
__global__ __launch_bounds__(256) void k_cvt(const float* __restrict__ src,
                                             unsigned short* __restrict__ dst,
                                             int count4) {
    int idx = blockIdx.x * 256 + threadIdx.x;
    if (idx < count4) {
        f32x4 v = ((const f32x4*)src)[idx];
        us4 o;
        o[0] = f2h(v[0]); o[1] = f2h(v[1]); o[2] = f2h(v[2]); o[3] = f2h(v[3]);
        ((us4*)dst)[idx] = o;
    }
}

// ---------------------------------------------------------------------------
// Kernel 0: x fp32 (b4, c, 14, 14) -> xjT fp16 (b, n=784, c) via LDS transpose
// ---------------------------------------------------------------------------
__global__ __launch_bounds__(256) void k_build_xjT(const float* __restrict__ x,
                                                   unsigned short* __restrict__ xjT) {
    __shared__ __align__(16) unsigned short lds[196 * 40];
    int c0 = blockIdx.x * 32;      // 48 c-tiles
    int b4 = blockIdx.y;           // 128 images
    int b = b4 >> 2, v = b4 & 3;
    int tid = threadIdx.x;
    const float* src = x + ((size_t)b4 * C_ + c0) * S_;
    for (int idx = tid; idx < 32 * 49; idx += 256) {
        int cl = idx / 49;
        int sq = idx - cl * 49;
        f32x4 val = *(const f32x4*)(src + (size_t)cl * S_ + sq * 4);
        int s = sq * 4;
        lds[(s + 0) * 40 + cl] = f2h(val[0]);
        lds[(s + 1) * 40 + cl] = f2h(val[1]);
        lds[(s + 2) * 40 + cl] = f2h(val[2]);
        lds[(s + 3) * 40 + cl] = f2h(val[3]);
    }
    __syncthreads();
    int rowbase = (v >> 1) * 14, colbase = (v & 1) * 14;
    for (int idx = tid; idx < 196 * 4; idx += 256) {
        int s = idx >> 2, ch = idx & 3;
        int hh = s / 14, ww = s - hh * 14;
        int n = (rowbase + hh) * 28 + colbase + ww;
        us8 val = *(const us8*)(&lds[s * 40 + ch * 8]);
        *(us8*)(xjT + ((size_t)b * N_ + n) * C_ + c0 + ch * 8) = val;
    }
}

// ---------------------------------------------------------------------------
// BN constant prep
// ---------------------------------------------------------------------------
__global__ __launch_bounds__(256) void k_bnprep(const float* __restrict__ bw,
                                                const float* __restrict__ gamma,
                                                const float* __restrict__ beta,
                                                const float* __restrict__ mean,
                                                const float* __restrict__ var,
                                                float* __restrict__ scale,
                                                float* __restrict__ shift) {
    int i = blockIdx.x * 256 + threadIdx.x;
    if (i < C_) {
        float sc = gamma[i] * rsqrtf(var[i] + 1e-5f);
        scale[i] = sc;
        shift[i] = (bw[i] - mean[i]) * sc + beta[i];
    }
}

// A+B-from-LDS compute (k_final): undo T2 swizzle via rcol.
#define COMPUTE_STEP4(As, Bs)                                                     \
    {                                                                             \
        f16x8 a0_ = *(const f16x8*)(&(As)[((wv * 4 + 0) * 16 + lr) * 32 + rcol]); \
        f16x8 a1_ = *(const f16x8*)(&(As)[((wv * 4 + 1) * 16 + lr) * 32 + rcol]); \
        f16x8 a2_ = *(const f16x8*)(&(As)[((wv * 4 + 2) * 16 + lr) * 32 + rcol]); \
        f16x8 a3_ = *(const f16x8*)(&(As)[((wv * 4 + 3) * 16 + lr) * 32 + rcol]); \
        _Pragma("unroll")                                                         \
        for (int j = 0; j < 7; ++j) {                                             \
            f16x8 bb = *(const f16x8*)(&(Bs)[(j * 16 + lr) * 32 + rcol]);         \
            acc[0][j] = mfma_f16(a0_, bb, acc[0][j]);                             \
            acc[1][j] = mfma_f16(a1_, bb, acc[1][j]);                             \
            acc[2][j] = mfma_f16(a2_, bb, acc[2][j]);                             \
            acc[3][j] = mfma_f16(a3_, bb, acc[3][j]);                             \
        }                                                                         \
    }

#define COMPUTE_STEP4P(As, Bs)                                                    \
    {                                                                             \
        __builtin_amdgcn_s_setprio(1);                                            \
        COMPUTE_STEP4(As, Bs);                                                    \
        __builtin_amdgcn_s_setprio(0);                                            \
    }

// Register-A compute (k_conv3): A-frags live in VGPRs; only B from LDS.
// 7 ds_read_b128 + 28 MFMA per wave per K-slice.
#define COMPUTE_REGA(Bs)                                                          \
    {                                                                             \
        __builtin_amdgcn_s_setprio(1);                                            \
        _Pragma("unroll")                                                         \
        for (int j = 0; j < 7; ++j) {                                             \
            f16x8 bb = *(const f16x8*)(&(Bs)[(j * 16 + lr) * 32 + rcol]);         \
            acc[0][j] = mfma_f16(aC0, bb, acc[0][j]);                             \
            acc[1][j] = mfma_f16(aC1, bb, acc[1][j]);                             \
            acc[2][j] = mfma_f16(aC2, bb, acc[2][j]);                             \
            acc[3][j] = mfma_f16(aC3, bb, acc[3][j]);                             \
        }                                                                         \
        __builtin_amdgcn_s_setprio(0);                                            \
    }

// ---------------------------------------------------------------------------
// Kernel 1: fused conv3 GEMM.  out[o,n] = bias[o] + sum_c wf[o,c]*xjT[n,c]
// M=2304, N=784, K=1536 per b.  Tile 256(o) x 112(n), 4 waves, 64x112/wave.
// A (weights) has ZERO intra-block LDS reuse -> loaded global->VGPR directly,
// prefetched one K-step ahead (weights L2-hot via XCD colocation).  B stays
// in double-buffered LDS (shared by 4 waves).  LDS traffic/block-step 67->35KB.
// T1: 1-D grid 2016, XCD decode, tm innermost (B-tile sharers on one XCD).
// ---------------------------------------------------------------------------
__global__ __launch_bounds__(256) void k_conv3(
    const unsigned short* __restrict__ xjT,
    const unsigned short* __restrict__ wf,      // (2304, 1536) fp16 stacked
    const float* __restrict__ b_theta, const float* __restrict__ b_phi,
    const float* __restrict__ b_g,
    unsigned short* __restrict__ theta_T, unsigned short* __restrict__ phi_p,
    unsigned short* __restrict__ g_p) {
    __shared__ __align__(16) unsigned char smem[28672];
    unsigned short* B0 = (unsigned short*)smem;   // 112 x 32 (7KB)
    unsigned short* B1 = B0 + 3584;               // 112 x 32 (7KB)
    float* fLDS = (float*)smem;                   // 64 x 112 fp32 (epilogue)

    // XCD-aware decode: f%8 = XCD, g = f/8; tm = g%9 (B-tile sharers adjacent)
    int f = blockIdx.x;                 // 0..2015
    int xcd = f & 7, g = f >> 3;        // g: 0..251
    int pg = g / 9, tm = g - pg * 9;    // pg: 0..27, tm: 0..8
    int pair = xcd * 28 + pg;           // 0..223  = (tn, b)
    int tn = pair % 7, b = pair / 7;

    int o0 = tm * 256, n0 = tn * 112;
    int region = o0 / 768;          // 0 theta, 1 phi, 2 g (3 tm-tiles each)
    int obase = o0 - region * 768;  // 0, 256, 512 within region
    const float* bias = (region == 0) ? b_theta : (region == 1) ? b_phi : b_g;

    int tid = threadIdx.x;
    int wv = tid >> 6, lane = tid & 63, lr = lane & 15, quad = lane >> 4;
    int l4r = lane >> 2, l4c = lane & 3;   // DMA chunk: 16 rows x 4 x 16B
    int l4c_sw = l4c ^ ((l4r >> 1) & 3);
    int rcol = (quad ^ ((lr >> 1) & 3)) * 8;

    f32x4 acc[4][7];
#pragma unroll
    for (int i = 0; i < 4; ++i)
#pragma unroll
        for (int j = 0; j < 7; ++j) acc[i][j] = (f32x4){0.f, 0.f, 0.f, 0.f};

    const unsigned short* Brow = xjT + ((size_t)b * N_ + n0) * C_;
    // per-lane A base: row = o0 + wv*64 + lr, col = quad*8 (+ i*16 rows, + k0)
    const unsigned short* Awq = wf + (size_t)(o0 + wv * 64 + lr) * C_ + quad * 8;

    // prologue: A frags for slice 0 + B slice 0
    f16x8 aC0 = *(const f16x8*)(Awq + 0 * 16 * C_);
    f16x8 aC1 = *(const f16x8*)(Awq + 1 * 16 * C_);
    f16x8 aC2 = *(const f16x8*)(Awq + 2 * 16 * C_);
    f16x8 aC3 = *(const f16x8*)(Awq + 3 * 16 * C_);
    stageB7(Brow, B0, 0, wv, l4r, l4c_sw);
    __syncthreads();
    for (int kk = 0; kk < 48; ++kk) {
        unsigned short* Bc = (kk & 1) ? B1 : B0;
        unsigned short* Bn = (kk & 1) ? B0 : B1;
        int k1 = (kk + 1 < 48) ? (kk + 1) * 32 : 47 * 32;
        if (kk + 1 < 48) stageB7(Brow, Bn, k1, wv, l4r, l4c_sw);
        f16x8 aN0 = *(const f16x8*)(Awq + k1 + 0 * 16 * C_);
        f16x8 aN1 = *(const f16x8*)(Awq + k1 + 1 * 16 * C_);
        f16x8 aN2 = *(const f16x8*)(Awq + k1 + 2 * 16 * C_);
        f16x8 aN3 = *(const f16x8*)(Awq + k1 + 3 * 16 * C_);
        COMPUTE_REGA(Bc);
        __syncthreads();            // drains: Bn staged + aN* in regs
        aC0 = aN0; aC1 = aN1; aC2 = aN2; aC3 = aN3;
    }

    // Epilogue: four 64-row chunks through fLDS; chunk h = wave h's acc.
    for (int h = 0; h < 4; ++h) {
        if (wv == h) {
#pragma unroll
            for (int i = 0; i < 4; ++i)
#pragma unroll
                for (int j = 0; j < 7; ++j)
#pragma unroll
                    for (int r = 0; r < 4; ++r) {
                        int o_rel = i * 16 + quad * 4 + r;   // 0..63
                        int n_l = j * 16 + lr;
                        fLDS[o_rel * 112 + n_l] = acc[i][j][r];
                    }
        }
        __syncthreads();
        if (region == 0) {
            for (int idx = tid; idx < 112 * 8; idx += 256) {
                int n_l = idx >> 3, ch = idx & 7;
                us8 outv;
#pragma unroll
                for (int k = 0; k < 8; ++k) {
                    int o_rel = ch * 8 + k;
                    float val = fLDS[o_rel * 112 + n_l] + bias[obase + h * 64 + o_rel];
                    outv[k] = f2h(val);
                }
                *(us8*)(theta_T + ((size_t)b * N_ + n0 + n_l) * CI_ + o0 + h * 64 + ch * 8) = outv;
            }
        } else if (region == 1) {
            for (int idx = tid; idx < 28 * 8; idx += 256) {
                int mm = idx >> 3, ch = idx & 7;
                int a = mm / 14, mw = mm - a * 14;
                int m = (tn * 2 + a) * 14 + mw;
                int sb = a * 56 + mw * 2;
                us8 outv;
#pragma unroll
                for (int k = 0; k < 8; ++k) {
                    int o_rel = ch * 8 + k;
                    const float* p = &fLDS[o_rel * 112 + sb];
                    float val = fmaxf(fmaxf(p[0], p[1]), fmaxf(p[28], p[29]));
                    val += bias[obase + h * 64 + o_rel];
                    outv[k] = f2h(val);
                }
                *(us8*)(phi_p + ((size_t)b * MP_ + m) * CI_ + obase + h * 64 + ch * 8) = outv;
            }
        } else {
            for (int idx = tid; idx < 128; idx += 256) {
                int o_rel = idx >> 1, a = idx & 1;
                int ci = obase + h * 64 + o_rel;
                unsigned short* dst = g_p + ((size_t)b * CI_ + ci) * MP_ + (tn * 2 + a) * 14;
                const float* p0 = &fLDS[o_rel * 112 + a * 56];
                float bv = bias[obase + h * 64 + o_rel];
#pragma unroll
                for (int mw = 0; mw < 14; ++mw) {
                    const float* p = p0 + mw * 2;
                    dst[mw] = f2h(fmaxf(fmaxf(p[0], p[1]), fmaxf(p[28], p[29])) + bv);
                }
            }
        }
        __syncthreads();
    }
}

// ---------------------------------------------------------------------------
// Kernel 2: fused attention per (b, 32-query tile).  Register GEMM straight
// from global.  T1: 1-D grid 800; the 25 blocks of a given b colocate on one
// XCD (phi_p+g_p = 0.7MB per b stays in that XCD's L2).
// ---------------------------------------------------------------------------
__global__ __launch_bounds__(256) void k_attn(
    const unsigned short* __restrict__ theta_T,
    const unsigned short* __restrict__ phi_p,
    const unsigned short* __restrict__ g_p,
    unsigned short* __restrict__ y) {
    __shared__ __align__(16) float f_s[32 * 228];

    int f = blockIdx.x;                 // 0..799
    int xcd = f & 7, g = f >> 3;        // g: 0..99
    int idx2 = xcd * 100 + g;           // 0..799
    int b = idx2 / 25, nb = idx2 - b * 25;
    int n0 = nb * 32;
    int tid = threadIdx.x, wv = tid >> 6, lane = tid & 63, lr = lane & 15, quad = lane >> 4;
    int mf0 = wv * 4;
    int nm = (mf0 + 4 <= 14) ? 4 : (14 - mf0);     // frags of keys: 4,4,4,2

    // A rows (queries), clamped for the last tile (rows >= 784 discarded later)
    int na0 = n0 + lr;       if (na0 > 783) na0 = 783;
    int na1 = n0 + 16 + lr;  if (na1 > 783) na1 = 783;
    const unsigned short* tA0 = theta_T + ((size_t)b * N_ + na0) * CI_ + quad * 8;
    const unsigned short* tA1 = theta_T + ((size_t)b * N_ + na1) * CI_ + quad * 8;

    f32x4 acc[2][4];
#pragma unroll
    for (int i = 0; i < 2; ++i)
#pragma unroll
        for (int j = 0; j < 4; ++j) acc[i][j] = (f32x4){0.f, 0.f, 0.f, 0.f};

    for (int kk = 0; kk < 24; ++kk) {
        int k0 = kk * 32;
        f16x8 a0 = *(const f16x8*)(tA0 + k0);
        f16x8 a1 = *(const f16x8*)(tA1 + k0);
        for (int j = 0; j < nm; ++j) {
            f16x8 bb = *(const f16x8*)(phi_p +
                ((size_t)b * MP_ + (mf0 + j) * 16 + lr) * CI_ + k0 + quad * 8);
            acc[0][j] = mfma_f16(a0, bb, acc[0][j]);
            acc[1][j] = mfma_f16(a1, bb, acc[1][j]);
        }
    }
    // dump f to LDS (fp32)
    for (int i = 0; i < 2; ++i)
        for (int j = 0; j < nm; ++j)
#pragma unroll
            for (int r = 0; r < 4; ++r)
                f_s[(i * 16 + quad * 4 + r) * 228 + (mf0 + j) * 16 + lr] = acc[i][j][r];
    __syncthreads();
    // softmax per query row over 196 real keys; zero the 28 pad keys.
    // 8 lanes per row (28 cols each), shfl_xor reduce within the 8-lane group.
    {
        int row = tid >> 3, sub = tid & 7;
        float* rowp = f_s + row * 228;
        int m0 = sub * 28;
        float mx = -1e30f;
#pragma unroll
        for (int m = 0; m < 28; ++m)
            if (m0 + m < MK_) mx = fmaxf(mx, rowp[m0 + m]);
        mx = fmaxf(mx, __shfl_xor(mx, 1));
        mx = fmaxf(mx, __shfl_xor(mx, 2));
        mx = fmaxf(mx, __shfl_xor(mx, 4));
        float sum = 0.f;
#pragma unroll
        for (int m = 0; m < 28; ++m) {
            float e = (m0 + m < MK_) ? __expf(rowp[m0 + m] - mx) : 0.f;
            rowp[m0 + m] = e;
            sum += e;
        }
        sum += __shfl_xor(sum, 1);
        sum += __shfl_xor(sum, 2);
        sum += __shfl_xor(sum, 4);
        float inv = 1.0f / sum;
#pragma unroll
        for (int m = 0; m < 28; ++m) rowp[m0 + m] *= inv;
    }
    __syncthreads();
    // phase 2: y[n, ci] = sum_m attn[n,m] * g_p[ci,m]; B-frags direct global
    for (int c3 = 0; c3 < 3; ++c3) {
        int ci0 = c3 * 256;
        f32x4 acc2[2][4];
#pragma unroll
        for (int i = 0; i < 2; ++i)
#pragma unroll
            for (int j = 0; j < 4; ++j) acc2[i][j] = (f32x4){0.f, 0.f, 0.f, 0.f};
        for (int km = 0; km < 7; ++km) {
            int k0 = km * 32;
            f16x8 a[2];
#pragma unroll
            for (int i = 0; i < 2; ++i) {
                const float* fp = &f_s[(i * 16 + lr) * 228 + k0 + quad * 8];
                f16x8 t;
#pragma unroll
                for (int j = 0; j < 8; ++j) t[j] = (_Float16)fp[j];
                a[i] = t;
            }
#pragma unroll
            for (int j = 0; j < 4; ++j) {
                f16x8 bb = *(const f16x8*)(g_p +
                    ((size_t)b * CI_ + ci0 + (wv * 4 + j) * 16 + lr) * MP_ + k0 + quad * 8);
                acc2[0][j] = mfma_f16(a[0], bb, acc2[0][j]);
                acc2[1][j] = mfma_f16(a[1], bb, acc2[1][j]);
            }
        }
#pragma unroll
        for (int i = 0; i < 2; ++i)
#pragma unroll
            for (int j = 0; j < 4; ++j)
#pragma unroll
                for (int r = 0; r < 4; ++r) {
                    int n = n0 + i * 16 + quad * 4 + r;
                    if (n < N_) {
                        int ci = ci0 + (wv * 4 + j) * 16 + lr;
                        y[((size_t)b * N_ + n) * CI_ + ci] = f2h(acc2[i][j][r]);
                    }
                }
    }
}

// ---------------------------------------------------------------------------
// Kernel 3: out = BN(wfW @ y) + xj.  M=1536, N=784, K=768 per batch.
// Tile 256 x 112 (6 tm tiles), 3-buffer counted-vmcnt pipeline.
// T1: 1-D grid 1344, XCD-aware decode, tm innermost.
// ---------------------------------------------------------------------------
__global__ __launch_bounds__(256, 2) void k_final(
    const unsigned short* __restrict__ yb,
    const unsigned short* __restrict__ wfW,     // (1536, 768) fp16
    const float* __restrict__ scale, const float* __restrict__ shift,
    const float* __restrict__ x,
    float* __restrict__ out) {
    __shared__ __align__(16) unsigned short smem_us[36864];
    unsigned short* A0 = smem_us;            // 256x32
    unsigned short* B0 = smem_us + 8192;     // 128x32 (112 valid)
    unsigned short* A1 = smem_us + 12288;
    unsigned short* B1 = smem_us + 20480;
    unsigned short* A2 = smem_us + 24576;
    unsigned short* B2 = smem_us + 32768;

    int f = blockIdx.x;                 // 0..1343
    int xcd = f & 7, g = f >> 3;        // g: 0..167
    int pg = g / 6, tm = g - pg * 6;    // pg: 0..27, tm: 0..5
    int pair = xcd * 28 + pg;           // 0..223
    int tn = pair % 7, b = pair / 7;

    int o0 = tm * 256, n0 = tn * 112;
    int tid = threadIdx.x, wv = tid >> 6, lane = tid & 63, lr = lane & 15, quad = lane >> 4;
    int l4r = lane >> 2, l4c = lane & 3;
    int l4c_sw = l4c ^ ((l4r >> 1) & 3);
    int rcol = (quad ^ ((lr >> 1) & 3)) * 8;

    f32x4 acc[4][7];
#pragma unroll
    for (int i = 0; i < 4; ++i)
#pragma unroll
        for (int j = 0; j < 7; ++j) acc[i][j] = (f32x4){0.f, 0.f, 0.f, 0.f};

    const unsigned short* Arow = wfW + (size_t)o0 * CI_;
    const unsigned short* Brow = yb + ((size_t)b * N_ + n0) * CI_;

    stage24(Arow, Brow, A0, B0, 0, CI_, wv, l4r, l4c_sw);
    stage24(Arow, Brow, A1, B1, 32, CI_, wv, l4r, l4c_sw);
    for (int kk = 0; kk < 24; kk += 3) {
        PIPE_WAIT_BARRIER();
        stage24(Arow, Brow, A2, B2, (kk + 2 < 24 ? kk + 2 : 23) * 32, CI_, wv, l4r, l4c_sw);
        COMPUTE_STEP4P(A0, B0);
        PIPE_WAIT_BARRIER();
        stage24(Arow, Brow, A0, B0, (kk + 3 < 24 ? kk + 3 : 23) * 32, CI_, wv, l4r, l4c_sw);
        COMPUTE_STEP4P(A1, B1);
        PIPE_WAIT_BARRIER();
        stage24(Arow, Brow, A1, B1, (kk + 4 < 24 ? kk + 4 : 23) * 32, CI_, wv, l4r, l4c_sw);
        COMPUTE_STEP4P(A2, B2);
    }
    asm volatile("s_waitcnt vmcnt(0)" ::: "memory");
    __syncthreads();
#pragma unroll
    for (int i = 0; i < 4; ++i)
#pragma unroll
        for (int r = 0; r < 4; ++r) {
            int o = o0 + (wv * 4 + i) * 16 + quad * 4 + r;
            float sc = scale[o], sh = shift[o];
#pragma unroll
            for (int j = 0; j < 7; ++j) {
                int n = n0 + j * 16 + lr;
                int hh = n / 28, ww = n - hh * 28;
                int vv = ((hh >= 14) ? 2 : 0) + ((ww >= 14) ? 1 : 0);
                int s = (hh - ((hh >= 14) ? 14 : 0)) * 14 + (ww - ((ww >= 14) ? 14 : 0));
                float xval = x[((size_t)(b * 4 + vv) * C_ + o) * S_ + s];
                out[((size_t)b * C_ + o) * N_ + n] = acc[i][j][r] * sc + sh + xval;
            }
        }
}

// ---------------------------------------------------------------------------
extern "C" void kernel_launch(void* const* d_in, const int* in_sizes, int n_in,
                              void* d_out, int out_size, void* d_ws, size_t ws_size,
                              hipStream_t stream) {
    (void)in_sizes; (void)n_in; (void)out_size; (void)ws_size;
    const float* x       = (const float*)d_in[0];
    const float* w_theta = (const float*)d_in[1];
    const float* b_theta = (const float*)d_in[2];
    const float* w_phi   = (const float*)d_in[3];
    const float* b_phi   = (const float*)d_in[4];
    const float* w_g     = (const float*)d_in[5];
    const float* b_g     = (const float*)d_in[6];
    const float* w_W     = (const float*)d_in[7];
    const float* b_W     = (const float*)d_in[8];
    const float* gamma   = (const float*)d_in[9];
    const float* beta    = (const float*)d_in[10];
    const float* mean    = (const float*)d_in[11];
    const float* var     = (const float*)d_in[12];

    // d_out (154,140,672 B fp32) as scratch for everything dead before k_final:
    char* ob = (char*)d_out;
    unsigned short* xjT     = (unsigned short*)(ob);              //  77,070,336 B
    unsigned short* theta_T = (unsigned short*)(ob + 77070336);   //  38,535,168 B
    unsigned short* phi_p   = (unsigned short*)(ob + 115605504);  //  11,010,048 B
    unsigned short* g_p     = (unsigned short*)(ob + 126615552);  //  11,010,048 B
    unsigned short* wf3     = (unsigned short*)(ob + 137625600);  //   7,077,888 B (ends 144,703,488)

    // d_ws: yb + fp16 wW + BN constants = ~40.9 MB
    char* ws = (char*)d_ws;
    unsigned short* yb    = (unsigned short*)(ws);                //  38,535,168 B
    unsigned short* wfW   = (unsigned short*)(ws + 38535168);     //   2,359,296 B
    float*          scale = (float*)(ws + 40894464);              //   6,144 B
    float*          shift = (float*)(ws + 40900608);              //   6,144 B

    // zero pooled buffers so the m=196..223 key padding is exactly 0
    hipMemsetAsync(phi_p, 0, 11010048, stream);
    hipMemsetAsync(g_p, 0, 11010048, stream);

    k_bnprep<<<6, 256, 0, stream>>>(b_W, gamma, beta, mean, var, scale, shift);
    // weight pre-convert: 768*1536/4 = 294912 units each; wW 1536*768/4
    k_cvt<<<1152, 256, 0, stream>>>(w_theta, wf3,                294912);
    k_cvt<<<1152, 256, 0, stream>>>(w_phi,   wf3 + 768 * 1536,   294912);
    k_cvt<<<1152, 256, 0, stream>>>(w_g,     wf3 + 2 * 768 * 1536, 294912);
    k_cvt<<<1152, 256, 0, stream>>>(w_W,     wfW,                294912);
    k_build_xjT<<<dim3(48, 128), 256, 0, stream>>>(x, xjT);
    k_conv3<<<2016, 256, 0, stream>>>(xjT, wf3, b_theta, b_phi, b_g,
                                      theta_T, phi_p, g_p);
    k_attn<<<800, 256, 0, stream>>>(theta_T, phi_p, g_p, yb);
    k_final<<<1344, 256, 0, stream>>>(yb, wfW, scale, shift, x,
                                      (float*)d_out);
}

// Round 7
// 755.312 us; speedup vs baseline: 1.0362x; 1.0362x over previous
//
#include <hip/hip_runtime.h>
#include <hip/hip_bf16.h>

typedef __attribute__((ext_vector_type(8))) _Float16 f16x8;
typedef __attribute__((ext_vector_type(4))) float f32x4;
typedef __attribute__((ext_vector_type(4))) unsigned short us4;
typedef __attribute__((ext_vector_type(8))) unsigned short us8;

#define B_   32
#define C_   1536
#define CI_  768
#define N_   784
#define S_   196
#define MP_  224
#define MK_  196

__device__ __forceinline__ unsigned short f2h(float f) {
    _Float16 h = (_Float16)f;      // v_cvt_f16_f32, RTNE
    return __builtin_bit_cast(unsigned short, h);
}
__device__ __forceinline__ f32x4 mfma_f16(f16x8 a, f16x8 b, f32x4 c) {
    return __builtin_amdgcn_mfma_f32_16x16x32_f16(a, b, c, 0, 0, 0);
}
// async 16B global->LDS: per-lane global addr, wave-uniform LDS base;
// HW writes lane l's 16B to base + l*16 (layouts below are lane-ordered).
__device__ __forceinline__ void gl_lds16(const unsigned short* g, unsigned short* l) {
    __builtin_amdgcn_global_load_lds(
        (const __attribute__((address_space(1))) unsigned int*)g,
        (__attribute__((address_space(3))) unsigned int*)l, 16, 0, 0);
}

// Stage A (256 rows) + B (128 rows, top 112 valid) one 32-wide K-slice:
// 24 chunks of 1KB (16 rows x 4 x 16B) -> exactly 6 chunks per wave, so
// vmcnt counts are wave-uniform.  B rows 112..127 are junk pad (stay inside
// mapped buffers; never consumed).
// T2 swizzle: source 16B-column is l4c ^ ((l4r>>1)&3); LDS linear; reader
// XORs back via rcol.
__device__ __forceinline__ void stage24(const unsigned short* Arow,
                                        const unsigned short* Brow,
                                        unsigned short* A_s, unsigned short* B_s,
                                        int k0, int stride,
                                        int wv, int l4r, int l4c_sw) {
    for (int c = wv; c < 24; c += 4) {
        if (c < 16) {
            gl_lds16(Arow + (size_t)(c * 16 + l4r) * stride + k0 + l4c_sw * 8,
                     A_s + c * 512);
        } else {
            int cb = c - 16;
            gl_lds16(Brow + (size_t)(cb * 16 + l4r) * stride + k0 + l4c_sw * 8,
                     B_s + cb * 512);
        }
    }
}

// Counted-wait (T4): own stage(t)'s 6 oldest drained, stage(t+1)'s 6 stay in
// flight; barrier then certifies all waves' stage(t) chunks are in LDS.
#define WAIT6_BARRIER()                                       \
    do {                                                      \
        asm volatile("s_waitcnt vmcnt(6)" ::: "memory");      \
        __builtin_amdgcn_sched_barrier(0);                    \
        __builtin_amdgcn_s_barrier();                         \
    } while (0)

// ---------------------------------------------------------------------------
// fp32 -> fp16 weight pre-convert (count4 = #float4 units)
// ---------------------------------------------------------------------------
__global__ __launch_bounds__(256) void k_cvt(const float* __restrict__ src,
                                             unsigned short* __restrict__ dst,
                                             int count4) {
    int idx = blockIdx.x * 256 + threadIdx.x;
    if (idx < count4) {
        f32x4 v = ((const f32x4*)src)[idx];
        us4 o;
        o[0] = f2h(v[0]); o[1] = f2h(v[1]); o[2] = f2h(v[2]); o[3] = f2h(v[3]);
        ((us4*)dst)[idx] = o;
    }
}

// ---------------------------------------------------------------------------
// Kernel 0: x fp32 (b4, c, 14, 14) -> xjT fp16 (b, n=784, c) via LDS transpose
// ---------------------------------------------------------------------------
__global__ __launch_bounds__(256) void k_build_xjT(const float* __restrict__ x,
                                                   unsigned short* __restrict__ xjT) {
    __shared__ __align__(16) unsigned short lds[196 * 40];
    int c0 = blockIdx.x * 32;      // 48 c-tiles
    int b4 = blockIdx.y;           // 128 images
    int b = b4 >> 2, v = b4 & 3;
    int tid = threadIdx.x;
    const float* src = x + ((size_t)b4 * C_ + c0) * S_;
    for (int idx = tid; idx < 32 * 49; idx += 256) {
        int cl = idx / 49;
        int sq = idx - cl * 49;
        f32x4 val = *(const f32x4*)(src + (size_t)cl * S_ + sq * 4);
        int s = sq * 4;
        lds[(s + 0) * 40 + cl] = f2h(val[0]);
        lds[(s + 1) * 40 + cl] = f2h(val[1]);
        lds[(s + 2) * 40 + cl] = f2h(val[2]);
        lds[(s + 3) * 40 + cl] = f2h(val[3]);
    }
    __syncthreads();
    int rowbase = (v >> 1) * 14, colbase = (v & 1) * 14;
    for (int idx = tid; idx < 196 * 4; idx += 256) {
        int s = idx >> 2, ch = idx & 3;
        int hh = s / 14, ww = s - hh * 14;
        int n = (rowbase + hh) * 28 + colbase + ww;
        us8 val = *(const us8*)(&lds[s * 40 + ch * 8]);
        *(us8*)(xjT + ((size_t)b * N_ + n) * C_ + c0 + ch * 8) = val;
    }
}

// ---------------------------------------------------------------------------
// BN constant prep
// ---------------------------------------------------------------------------
__global__ __launch_bounds__(256) void k_bnprep(const float* __restrict__ bw,
                                                const float* __restrict__ gamma,
                                                const float* __restrict__ beta,
                                                const float* __restrict__ mean,
                                                const float* __restrict__ var,
                                                float* __restrict__ scale,
                                                float* __restrict__ shift) {
    int i = blockIdx.x * 256 + threadIdx.x;
    if (i < C_) {
        float sc = gamma[i] * rsqrtf(var[i] + 1e-5f);
        scale[i] = sc;
        shift[i] = (bw[i] - mean[i]) * sc + beta[i];
    }
}

// Fragment reads: undo the T2 staging swizzle (rcol = (quad^((lr>>1)&3))*8).
// Each wave: 64 output rows (4 frags) x 112 cols (7 frags) = 28 MFMA per
// K-slice against 11 ds_read_b128.
#define COMPUTE_STEP4(As, Bs)                                                     \
    {                                                                             \
        f16x8 a0_ = *(const f16x8*)(&(As)[((wv * 4 + 0) * 16 + lr) * 32 + rcol]); \
        f16x8 a1_ = *(const f16x8*)(&(As)[((wv * 4 + 1) * 16 + lr) * 32 + rcol]); \
        f16x8 a2_ = *(const f16x8*)(&(As)[((wv * 4 + 2) * 16 + lr) * 32 + rcol]); \
        f16x8 a3_ = *(const f16x8*)(&(As)[((wv * 4 + 3) * 16 + lr) * 32 + rcol]); \
        _Pragma("unroll")                                                         \
        for (int j = 0; j < 7; ++j) {                                             \
            f16x8 bb = *(const f16x8*)(&(Bs)[(j * 16 + lr) * 32 + rcol]);         \
            acc[0][j] = mfma_f16(a0_, bb, acc[0][j]);                             \
            acc[1][j] = mfma_f16(a1_, bb, acc[1][j]);                             \
            acc[2][j] = mfma_f16(a2_, bb, acc[2][j]);                             \
            acc[3][j] = mfma_f16(a3_, bb, acc[3][j]);                             \
        }                                                                         \
    }

// With T5 setprio around the MFMA cluster (counted schedules only).
#define COMPUTE_STEP4P(As, Bs)                                                    \
    {                                                                             \
        __builtin_amdgcn_s_setprio(1);                                            \
        COMPUTE_STEP4(As, Bs);                                                    \
        __builtin_amdgcn_s_setprio(0);                                            \
    }

// ---------------------------------------------------------------------------
// Kernel 1: fused conv3 GEMM.  out[o,n] = bias[o] + sum_c wf[o,c]*xjT[n,c]
// M=2304, N=784, K=1536 per b.  Tile 256(o) x 112(n), 4 waves, 64x112/wave.
// Counted 2-buffer pipeline (48KB LDS, 3 blocks/CU): per K-step
//   barrier(buf free) -> stage(t+1) -> vmcnt(6) [stage(t) landed, stage(t+1)
//   in flight] -> barrier -> MFMA(t).   Never vmcnt(0) in the loop (T4).
// T1: 1-D grid 2016, XCD decode, tm innermost (B-tile sharers on one XCD).
// ---------------------------------------------------------------------------
__global__ __launch_bounds__(256, 3) void k_conv3(
    const unsigned short* __restrict__ xjT,
    const unsigned short* __restrict__ wf,      // (2304, 1536) fp16 stacked
    const float* __restrict__ b_theta, const float* __restrict__ b_phi,
    const float* __restrict__ b_g,
    unsigned short* __restrict__ theta_T, unsigned short* __restrict__ phi_p,
    unsigned short* __restrict__ g_p) {
    __shared__ __align__(16) unsigned char smem[49152];
    unsigned short* A0 = (unsigned short*)smem;   // 256x32 (16KB)
    unsigned short* B0 = A0 + 8192;               // 128x32 (8KB, 112 valid)
    unsigned short* A1 = A0 + 12288;
    unsigned short* B1 = A0 + 20480;
    float* fLDS = (float*)smem;                   // 64 x 112 fp32 (epilogue)

    // XCD-aware decode: f%8 = XCD, g = f/8; tm = g%9 (B-tile sharers adjacent)
    int f = blockIdx.x;                 // 0..2015
    int xcd = f & 7, g = f >> 3;        // g: 0..251
    int pg = g / 9, tm = g - pg * 9;    // pg: 0..27, tm: 0..8
    int pair = xcd * 28 + pg;           // 0..223  = (tn, b)
    int tn = pair % 7, b = pair / 7;

    int o0 = tm * 256, n0 = tn * 112;
    int region = o0 / 768;          // 0 theta, 1 phi, 2 g (3 tm-tiles each)
    int obase = o0 - region * 768;  // 0, 256, 512 within region
    const float* bias = (region == 0) ? b_theta : (region == 1) ? b_phi : b_g;

    int tid = threadIdx.x;
    int wv = tid >> 6, lane = tid & 63, lr = lane & 15, quad = lane >> 4;
    int l4r = lane >> 2, l4c = lane & 3;   // DMA chunk: 16 rows x 4 x 16B
    int l4c_sw = l4c ^ ((l4r >> 1) & 3);
    int rcol = (quad ^ ((lr >> 1) & 3)) * 8;

    f32x4 acc[4][7];
#pragma unroll
    for (int i = 0; i < 4; ++i)
#pragma unroll
        for (int j = 0; j < 7; ++j) acc[i][j] = (f32x4){0.f, 0.f, 0.f, 0.f};

    const unsigned short* Arow = wf + (size_t)o0 * C_;
    const unsigned short* Brow = xjT + ((size_t)b * N_ + n0) * C_;

    // prologue: slice 0 -> buf0 (6 outstanding/wave)
    stage24(Arow, Brow, A0, B0, 0, C_, wv, l4r, l4c_sw);
    for (int kk = 0; kk < 48; kk += 2) {
        __builtin_amdgcn_s_barrier();            // computes of kk-1 done: buf1 free
        stage24(Arow, Brow, A1, B1, (kk + 1 < 48 ? kk + 1 : 47) * 32, C_, wv, l4r, l4c_sw);
        WAIT6_BARRIER();                         // slice kk landed everywhere
        COMPUTE_STEP4P(A0, B0);
        __builtin_amdgcn_s_barrier();            // buf0 free
        stage24(Arow, Brow, A0, B0, (kk + 2 < 48 ? kk + 2 : 47) * 32, C_, wv, l4r, l4c_sw);
        WAIT6_BARRIER();                         // slice kk+1 landed
        COMPUTE_STEP4P(A1, B1);
    }
    asm volatile("s_waitcnt vmcnt(0)" ::: "memory");   // drain tail dummies
    __syncthreads();

    // Epilogue: four 64-row chunks through fLDS; chunk h = wave h's acc.
    for (int h = 0; h < 4; ++h) {
        if (wv == h) {
#pragma unroll
            for (int i = 0; i < 4; ++i)
#pragma unroll
                for (int j = 0; j < 7; ++j)
#pragma unroll
                    for (int r = 0; r < 4; ++r) {
                        int o_rel = i * 16 + quad * 4 + r;   // 0..63
                        int n_l = j * 16 + lr;
                        fLDS[o_rel * 112 + n_l] = acc[i][j][r];
                    }
        }
        __syncthreads();
        if (region == 0) {
            for (int idx = tid; idx < 112 * 8; idx += 256) {
                int n_l = idx >> 3, ch = idx & 7;
                us8 outv;
#pragma unroll
                for (int k = 0; k < 8; ++k) {
                    int o_rel = ch * 8 + k;
                    float val = fLDS[o_rel * 112 + n_l] + bias[obase + h * 64 + o_rel];
                    outv[k] = f2h(val);
                }
                *(us8*)(theta_T + ((size_t)b * N_ + n0 + n_l) * CI_ + o0 + h * 64 + ch * 8) = outv;
            }
        } else if (region == 1) {
            for (int idx = tid; idx < 28 * 8; idx += 256) {
                int mm = idx >> 3, ch = idx & 7;
                int a = mm / 14, mw = mm - a * 14;
                int m = (tn * 2 + a) * 14 + mw;
                int sb = a * 56 + mw * 2;
                us8 outv;
#pragma unroll
                for (int k = 0; k < 8; ++k) {
                    int o_rel = ch * 8 + k;
                    const float* p = &fLDS[o_rel * 112 + sb];
                    float val = fmaxf(fmaxf(p[0], p[1]), fmaxf(p[28], p[29]));
                    val += bias[obase + h * 64 + o_rel];
                    outv[k] = f2h(val);
                }
                *(us8*)(phi_p + ((size_t)b * MP_ + m) * CI_ + obase + h * 64 + ch * 8) = outv;
            }
        } else {
            for (int idx = tid; idx < 128; idx += 256) {
                int o_rel = idx >> 1, a = idx & 1;
                int ci = obase + h * 64 + o_rel;
                unsigned short* dst = g_p + ((size_t)b * CI_ + ci) * MP_ + (tn * 2 + a) * 14;
                const float* p0 = &fLDS[o_rel * 112 + a * 56];
                float bv = bias[obase + h * 64 + o_rel];
#pragma unroll
                for (int mw = 0; mw < 14; ++mw) {
                    const float* p = p0 + mw * 2;
                    dst[mw] = f2h(fmaxf(fmaxf(p[0], p[1]), fmaxf(p[28], p[29])) + bv);
                }
            }
        }
        __syncthreads();
    }
}

// ---------------------------------------------------------------------------
// Kernel 2: fused attention per (b, 32-query tile).  Register GEMM straight
// from global.  T1: 1-D grid 800; the 25 blocks of a given b colocate on one
// XCD.  Softmax fully in registers (8 lanes/row); P converted to fp16 ONCE
// into a [32][232] LDS buffer (aliases f_s) -> phase-2 A-frags are single
// ds_read_b128 instead of 8x ds_read_b32 + cvt per frag per wave.
// ---------------------------------------------------------------------------
__global__ __launch_bounds__(256) void k_attn(
    const unsigned short* __restrict__ theta_T,
    const unsigned short* __restrict__ phi_p,
    const unsigned short* __restrict__ g_p,
    unsigned short* __restrict__ y) {
    __shared__ __align__(16) float f_s[32 * 228];

    int f = blockIdx.x;                 // 0..799
    int xcd = f & 7, g = f >> 3;        // g: 0..99
    int idx2 = xcd * 100 + g;           // 0..799
    int b = idx2 / 25, nb = idx2 - b * 25;
    int n0 = nb * 32;
    int tid = threadIdx.x, wv = tid >> 6, lane = tid & 63, lr = lane & 15, quad = lane >> 4;
    int mf0 = wv * 4;
    int nm = (mf0 + 4 <= 14) ? 4 : (14 - mf0);     // frags of keys: 4,4,4,2

    // A rows (queries), clamped for the last tile (rows >= 784 discarded later)
    int na0 = n0 + lr;       if (na0 > 783) na0 = 783;
    int na1 = n0 + 16 + lr;  if (na1 > 783) na1 = 783;
    const unsigned short* tA0 = theta_T + ((size_t)b * N_ + na0) * CI_ + quad * 8;
    const unsigned short* tA1 = theta_T + ((size_t)b * N_ + na1) * CI_ + quad * 8;

    f32x4 acc[2][4];
#pragma unroll
    for (int i = 0; i < 2; ++i)
#pragma unroll
        for (int j = 0; j < 4; ++j) acc[i][j] = (f32x4){0.f, 0.f, 0.f, 0.f};

    for (int kk = 0; kk < 24; ++kk) {
        int k0 = kk * 32;
        f16x8 a0 = *(const f16x8*)(tA0 + k0);
        f16x8 a1 = *(const f16x8*)(tA1 + k0);
        for (int j = 0; j < nm; ++j) {
            f16x8 bb = *(const f16x8*)(phi_p +
                ((size_t)b * MP_ + (mf0 + j) * 16 + lr) * CI_ + k0 + quad * 8);
            acc[0][j] = mfma_f16(a0, bb, acc[0][j]);
            acc[1][j] = mfma_f16(a1, bb, acc[1][j]);
        }
    }
    // dump f to LDS (fp32)
    for (int i = 0; i < 2; ++i)
        for (int j = 0; j < nm; ++j)
#pragma unroll
            for (int r = 0; r < 4; ++r)
                f_s[(i * 16 + quad * 4 + r) * 228 + (mf0 + j) * 16 + lr] = acc[i][j][r];
    __syncthreads();
    // softmax in registers: 8 lanes per query row (28 cols each), shfl_xor
    // reduce; then write normalized P as fp16 into P16[32][232] (aliases f_s
    // after the mid-barrier).  Pad keys m=196..223 become exact 0.
    {
        int row = tid >> 3, sub = tid & 7;
        const float* rowp = f_s + row * 228;
        int m0 = sub * 28;
        float v[28];
#pragma unroll
        for (int m = 0; m < 28; ++m) v[m] = rowp[m0 + m];
        __syncthreads();                     // all fp32 reads done; f_s reusable
        float mx = -1e30f;
#pragma unroll
        for (int m = 0; m < 28; ++m)
            if (m0 + m < MK_) mx = fmaxf(mx, v[m]);
        mx = fmaxf(mx, __shfl_xor(mx, 1));
        mx = fmaxf(mx, __shfl_xor(mx, 2));
        mx = fmaxf(mx, __shfl_xor(mx, 4));
        float sum = 0.f;
#pragma unroll
        for (int m = 0; m < 28; ++m) {
            float e = (m0 + m < MK_) ? __expf(v[m] - mx) : 0.f;
            v[m] = e;
            sum += e;
        }
        sum += __shfl_xor(sum, 1);
        sum += __shfl_xor(sum, 2);
        sum += __shfl_xor(sum, 4);
        float inv = 1.0f / sum;
        unsigned short* P16 = (unsigned short*)f_s;   // [32][232] fp16
#pragma unroll
        for (int q = 0; q < 7; ++q) {
            us4 ov;
#pragma unroll
            for (int r = 0; r < 4; ++r) ov[r] = f2h(v[q * 4 + r] * inv);
            *(us4*)(P16 + row * 232 + m0 + q * 4) = ov;
        }
    }
    __syncthreads();
    // phase 2: y[n, ci] = sum_m P[n,m] * g_p[ci,m]; A-frags via ds_read_b128
    const unsigned short* P16 = (const unsigned short*)f_s;
    for (int c3 = 0; c3 < 3; ++c3) {
        int ci0 = c3 * 256;
        f32x4 acc2[2][4];
#pragma unroll
        for (int i = 0; i < 2; ++i)
#pragma unroll
            for (int j = 0; j < 4; ++j) acc2[i][j] = (f32x4){0.f, 0.f, 0.f, 0.f};
        for (int km = 0; km < 7; ++km) {
            int k0 = km * 32;
            f16x8 a0 = *(const f16x8*)(P16 + (0 * 16 + lr) * 232 + k0 + quad * 8);
            f16x8 a1 = *(const f16x8*)(P16 + (1 * 16 + lr) * 232 + k0 + quad * 8);
#pragma unroll
            for (int j = 0; j < 4; ++j) {
                f16x8 bb = *(const f16x8*)(g_p +
                    ((size_t)b * CI_ + ci0 + (wv * 4 + j) * 16 + lr) * MP_ + k0 + quad * 8);
                acc2[0][j] = mfma_f16(a0, bb, acc2[0][j]);
                acc2[1][j] = mfma_f16(a1, bb, acc2[1][j]);
            }
        }
#pragma unroll
        for (int i = 0; i < 2; ++i)
#pragma unroll
            for (int j = 0; j < 4; ++j)
#pragma unroll
                for (int r = 0; r < 4; ++r) {
                    int n = n0 + i * 16 + quad * 4 + r;
                    if (n < N_) {
                        int ci = ci0 + (wv * 4 + j) * 16 + lr;
                        y[((size_t)b * N_ + n) * CI_ + ci] = f2h(acc2[i][j][r]);
                    }
                }
    }
}

// ---------------------------------------------------------------------------
// Kernel 3: out = BN(wfW @ y) + xj.  M=1536, N=784, K=768 per batch.
// Tile 256 x 112 (6 tm tiles), 3-buffer counted-vmcnt pipeline.
// T1: 1-D grid 1344, XCD-aware decode, tm innermost.
// ---------------------------------------------------------------------------
__global__ __launch_bounds__(256, 2) void k_final(
    const unsigned short* __restrict__ yb,
    const unsigned short* __restrict__ wfW,     // (1536, 768) fp16
    const float* __restrict__ scale, const float* __restrict__ shift,
    const float* __restrict__ x,
    float* __restrict__ out) {
    __shared__ __align__(16) unsigned short smem_us[36864];
    unsigned short* A0 = smem_us;            // 256x32
    unsigned short* B0 = smem_us + 8192;     // 128x32 (112 valid)
    unsigned short* A1 = smem_us + 12288;
    unsigned short* B1 = smem_us + 20480;
    unsigned short* A2 = smem_us + 24576;
    unsigned short* B2 = smem_us + 32768;

    int f = blockIdx.x;                 // 0..1343
    int xcd = f & 7, g = f >> 3;        // g: 0..167
    int pg = g / 6, tm = g - pg * 6;    // pg: 0..27, tm: 0..5
    int pair = xcd * 28 + pg;           // 0..223
    int tn = pair % 7, b = pair / 7;

    int o0 = tm * 256, n0 = tn * 112;
    int tid = threadIdx.x, wv = tid >> 6, lane = tid & 63, lr = lane & 15, quad = lane >> 4;
    int l4r = lane >> 2, l4c = lane & 3;
    int l4c_sw = l4c ^ ((l4r >> 1) & 3);
    int rcol = (quad ^ ((lr >> 1) & 3)) * 8;

    f32x4 acc[4][7];
#pragma unroll
    for (int i = 0; i < 4; ++i)
#pragma unroll
        for (int j = 0; j < 7; ++j) acc[i][j] = (f32x4){0.f, 0.f, 0.f, 0.f};

    const unsigned short* Arow = wfW + (size_t)o0 * CI_;
    const unsigned short* Brow = yb + ((size_t)b * N_ + n0) * CI_;

    stage24(Arow, Brow, A0, B0, 0, CI_, wv, l4r, l4c_sw);
    stage24(Arow, Brow, A1, B1, 32, CI_, wv, l4r, l4c_sw);
    for (int kk = 0; kk < 24; kk += 3) {
        WAIT6_BARRIER();
        stage24(Arow, Brow, A2, B2, (kk + 2 < 24 ? kk + 2 : 23) * 32, CI_, wv, l4r, l4c_sw);
        COMPUTE_STEP4P(A0, B0);
        WAIT6_BARRIER();
        stage24(Arow, Brow, A0, B0, (kk + 3 < 24 ? kk + 3 : 23) * 32, CI_, wv, l4r, l4c_sw);
        COMPUTE_STEP4P(A1, B1);
        WAIT6_BARRIER();
        stage24(Arow, Brow, A1, B1, (kk + 4 < 24 ? kk + 4 : 23) * 32, CI_, wv, l4r, l4c_sw);
        COMPUTE_STEP4P(A2, B2);
    }
    asm volatile("s_waitcnt vmcnt(0)" ::: "memory");
    __syncthreads();
#pragma unroll
    for (int i = 0; i < 4; ++i)
#pragma unroll
        for (int r = 0; r < 4; ++r) {
            int o = o0 + (wv * 4 + i) * 16 + quad * 4 + r;
            float sc = scale[o], sh = shift[o];
#pragma unroll
            for (int j = 0; j < 7; ++j) {
                int n = n0 + j * 16 + lr;
                int hh = n / 28, ww = n - hh * 28;
                int vv = ((hh >= 14) ? 2 : 0) + ((ww >= 14) ? 1 : 0);
                int s = (hh - ((hh >= 14) ? 14 : 0)) * 14 + (ww - ((ww >= 14) ? 14 : 0));
                float xval = x[((size_t)(b * 4 + vv) * C_ + o) * S_ + s];
                out[((size_t)b * C_ + o) * N_ + n] = acc[i][j][r] * sc + sh + xval;
            }
        }
}

// ---------------------------------------------------------------------------
extern "C" void kernel_launch(void* const* d_in, const int* in_sizes, int n_in,
                              void* d_out, int out_size, void* d_ws, size_t ws_size,
                              hipStream_t stream) {
    (void)in_sizes; (void)n_in; (void)out_size; (void)ws_size;
    const float* x       = (const float*)d_in[0];
    const float* w_theta = (const float*)d_in[1];
    const float* b_theta = (const float*)d_in[2];
    const float* w_phi   = (const float*)d_in[3];
    const float* b_phi   = (const float*)d_in[4];
    const float* w_g     = (const float*)d_in[5];
    const float* b_g     = (const float*)d_in[6];
    const float* w_W     = (const float*)d_in[7];
    const float* b_W     = (const float*)d_in[8];
    const float* gamma   = (const float*)d_in[9];
    const float* beta    = (const float*)d_in[10];
    const float* mean    = (const float*)d_in[11];
    const float* var     = (const float*)d_in[12];

    // d_out (154,140,672 B fp32) as scratch for everything dead before k_final:
    char* ob = (char*)d_out;
    unsigned short* xjT     = (unsigned short*)(ob);              //  77,070,336 B
    unsigned short* theta_T = (unsigned short*)(ob + 77070336);   //  38,535,168 B
    unsigned short* phi_p   = (unsigned short*)(ob + 115605504);  //  11,010,048 B
    unsigned short* g_p     = (unsigned short*)(ob + 126615552);  //  11,010,048 B
    unsigned short* wf3     = (unsigned short*)(ob + 137625600);  //   7,077,888 B (ends 144,703,488)

    // d_ws: yb + fp16 wW + BN constants = ~40.9 MB
    char* ws = (char*)d_ws;
    unsigned short* yb    = (unsigned short*)(ws);                //  38,535,168 B
    unsigned short* wfW   = (unsigned short*)(ws + 38535168);     //   2,359,296 B
    float*          scale = (float*)(ws + 40894464);              //   6,144 B
    float*          shift = (float*)(ws + 40900608);              //   6,144 B

    // zero pooled buffers so the m=196..223 key padding is exactly 0
    hipMemsetAsync(phi_p, 0, 11010048, stream);
    hipMemsetAsync(g_p, 0, 11010048, stream);

    k_bnprep<<<6, 256, 0, stream>>>(b_W, gamma, beta, mean, var, scale, shift);
    // weight pre-convert: 768*1536/4 = 294912 units each; wW 1536*768/4
    k_cvt<<<1152, 256, 0, stream>>>(w_theta, wf3,                294912);
    k_cvt<<<1152, 256, 0, stream>>>(w_phi,   wf3 + 768 * 1536,   294912);
    k_cvt<<<1152, 256, 0, stream>>>(w_g,     wf3 + 2 * 768 * 1536, 294912);
    k_cvt<<<1152, 256, 0, stream>>>(w_W,     wfW,                294912);
    k_build_xjT<<<dim3(48, 128), 256, 0, stream>>>(x, xjT);
    k_conv3<<<2016, 256, 0, stream>>>(xjT, wf3, b_theta, b_phi, b_g,
                                      theta_T, phi_p, g_p);
    k_attn<<<800, 256, 0, stream>>>(theta_T, phi_p, g_p, yb);
    k_final<<<1344, 256, 0, stream>>>(yb, wfW, scale, shift, x,
                                      (float*)d_out);
}